// Round 1
// baseline (726.094 us; speedup 1.0000x reference)
//
#include <hip/hip_runtime.h>

// Fused Canny-style edge pipeline for 1x3x4096x4096 fp32 input.
// Single kernel: per 64x64 output tile, stage hblur/blur/mag in LDS.

#define IMG_H 4096
#define IMG_W 4096

constexpr int TW = 64, TH = 64;
constexpr int HBW = TW + 4;   // 68: hblur tile width  (cols X0-2 .. X0+TW+2)
constexpr int HBH = TH + 8;   // 72: hblur tile height (rows Y0-4 .. Y0+TH+4)
constexpr int BW  = TW + 4;   // 68: blurred tile (rows/cols offset -2)
constexpr int BH  = TH + 4;   // 68
constexpr int MW  = TW + 2;   // 66: grad_mag tile (offset -1)
constexpr int MH  = TH + 2;   // 66

__global__ __launch_bounds__(256)
void canny_fused(const float* __restrict__ img,
                 const float* __restrict__ gauss,
                 float* __restrict__ out) {
  __shared__ float s_hb[HBH * HBW];  // per-channel horizontal blur
  __shared__ float s_bl[BH * BW];    // per-channel blurred
  __shared__ float s_bs[BH * BW];    // sum over channels of blurred
  __shared__ float s_mg[MH * MW];    // grad_mag (summed over channels)

  const int tid = threadIdx.x;
  const int X0 = blockIdx.x * TW;
  const int Y0 = blockIdx.y * TH;

  const float g0 = gauss[0], g1 = gauss[1], g2 = gauss[2],
              g3 = gauss[3], g4 = gauss[4];

  for (int ch = 0; ch < 3; ++ch) {
    const float* im = img + (size_t)ch * IMG_H * IMG_W;

    // Stage A: horizontal gaussian. hblur rel (r,c) = abs (Y0-4+r, X0-2+c).
    // Out-of-image rows -> 0 (vertical conv zero-pads its input).
    for (int i = tid; i < HBH * HBW; i += 256) {
      int r = i / HBW, c = i - r * HBW;
      int gy = Y0 - 4 + r;
      float v = 0.f;
      if ((unsigned)gy < IMG_H) {
        int gx0 = X0 - 4 + c;  // leftmost tap column
        const float* row = im + (size_t)gy * IMG_W;
        float a0 = ((unsigned)(gx0    ) < IMG_W) ? row[gx0    ] : 0.f;
        float a1 = ((unsigned)(gx0 + 1) < IMG_W) ? row[gx0 + 1] : 0.f;
        float a2 = ((unsigned)(gx0 + 2) < IMG_W) ? row[gx0 + 2] : 0.f;
        float a3 = ((unsigned)(gx0 + 3) < IMG_W) ? row[gx0 + 3] : 0.f;
        float a4 = ((unsigned)(gx0 + 4) < IMG_W) ? row[gx0 + 4] : 0.f;
        v = g0 * a0 + g1 * a1 + g2 * a2 + g3 * a3 + g4 * a4;
      }
      s_hb[i] = v;
    }
    __syncthreads();

    // Stage B: vertical gaussian. blur rel (r,c) = abs (Y0-2+r, X0-2+c).
    // Force exact 0 outside the image: the Sobel conv zero-pads *blurred*.
    for (int i = tid; i < BH * BW; i += 256) {
      int r = i / BW, c = i - r * BW;
      int gy = Y0 - 2 + r, gx = X0 - 2 + c;
      float v = 0.f;
      if ((unsigned)gy < IMG_H && (unsigned)gx < IMG_W) {
        v = g0 * s_hb[(r    ) * HBW + c] + g1 * s_hb[(r + 1) * HBW + c]
          + g2 * s_hb[(r + 2) * HBW + c] + g3 * s_hb[(r + 3) * HBW + c]
          + g4 * s_hb[(r + 4) * HBW + c];
      }
      s_bl[i] = v;
      if (ch == 0) s_bs[i] = v; else s_bs[i] += v;
    }
    __syncthreads();

    // Stage C: Sobel + per-channel magnitude. mag rel (r,c) = abs (Y0-1+r, X0-1+c).
    // Force exact 0 outside image (dir conv zero-pads grad_mag).
    for (int i = tid; i < MH * MW; i += 256) {
      int r = i / MW, c = i - r * MW;
      int gy = Y0 - 1 + r, gx = X0 - 1 + c;
      float m = 0.f;
      if ((unsigned)gy < IMG_H && (unsigned)gx < IMG_W) {
        float b00 = s_bl[(r    ) * BW + c], b01 = s_bl[(r    ) * BW + c + 1], b02 = s_bl[(r    ) * BW + c + 2];
        float b10 = s_bl[(r + 1) * BW + c],                                   b12 = s_bl[(r + 1) * BW + c + 2];
        float b20 = s_bl[(r + 2) * BW + c], b21 = s_bl[(r + 2) * BW + c + 1], b22 = s_bl[(r + 2) * BW + c + 2];
        float gxv = b00 - b02 + 2.f * b10 - 2.f * b12 + b20 - b22;  // sobel
        float gyv = b00 + 2.f * b01 + b02 - b20 - 2.f * b21 - b22;  // sobel^T
        m = sqrtf(gxv * gxv + gyv * gyv + 1e-8f);
      }
      if (ch == 0) s_mg[i] = m; else s_mg[i] += m;
    }
    __syncthreads();
  }

  // Stage D: orientation + directional NMS + threshold, per output pixel.
  // dir_w[k] = center - neighbor_k; neighbor offsets (dr,dc) packed as
  // int8 linear LDS offsets dr*MW+dc: k=0..7 -> 1,67,66,65,-1,-67,-66,-65.
  // idx_neg = idx_pos + 4 (mod 8) is exactly the opposite offset.
  const unsigned long long off_tbl = 0xBFBEBDFF41424301ULL;
  for (int i = tid; i < TH * TW; i += 256) {
    int ty = i >> 6, tx = i & 63;

    int rb = ty + 1, cb = tx + 1;  // blur-rel coords of (oy-1, ox-1)
    float b00 = s_bs[(rb    ) * BW + cb], b01 = s_bs[(rb    ) * BW + cb + 1], b02 = s_bs[(rb    ) * BW + cb + 2];
    float b10 = s_bs[(rb + 1) * BW + cb],                                     b12 = s_bs[(rb + 1) * BW + cb + 2];
    float b20 = s_bs[(rb + 2) * BW + cb], b21 = s_bs[(rb + 2) * BW + cb + 1], b22 = s_bs[(rb + 2) * BW + cb + 2];
    float gxs = b00 - b02 + 2.f * b10 - 2.f * b12 + b20 - b22;
    float gys = b00 + 2.f * b01 + b02 - b20 - 2.f * b21 - b22;

    float ori = atan2f(gys, gxs) * 57.295827908797776f + 180.0f;  // 180/3.14159
    int k = (int)rintf(ori / 45.0f);          // 0..8, round-half-even like jnp.round
    int ip = k & 7;
    int off = (int)(signed char)(off_tbl >> (ip * 8));

    int ctr = (ty + 1) * MW + (tx + 1);
    float mc = s_mg[ctr];
    float csp = mc - s_mg[ctr + off];
    float csn = mc - s_mg[ctr - off];
    bool is_max = fminf(csp, csn) > 0.0f;
    float thin = is_max ? mc : 0.0f;
    bool keep = is_max && (thin >= 6.0f) && (thin <= 50.0f);
    out[(size_t)(Y0 + ty) * IMG_W + (X0 + tx)] = keep ? 1.0f : 0.0f;
  }
}

extern "C" void kernel_launch(void* const* d_in, const int* in_sizes, int n_in,
                              void* d_out, int out_size, void* d_ws, size_t ws_size,
                              hipStream_t stream) {
  const float* img   = (const float*)d_in[0];
  const float* gauss = (const float*)d_in[1];
  float* out = (float*)d_out;
  dim3 grid(IMG_W / TW, IMG_H / TH);
  canny_fused<<<grid, 256, 0, stream>>>(img, gauss, out);
}

// Round 2
// 370.858 us; speedup vs baseline: 1.9579x; 1.9579x over previous
//
#include <hip/hip_runtime.h>

// Fused Canny-style edge pipeline, 1x3x4096x4096 fp32 -> 1x4096x4096 fp32.
// R2: 32x32 tile, group-of-4-column vectorization, 22.8 KB LDS (6-7 blocks/CU).

#define IMG_H 4096
#define IMG_W 4096

constexpr int TW = 32, TH = 32;
constexpr int HBH = 40, HBW = 40;  // hblur:   (r,c) -> abs (Y0-4+r, X0-2+c)
constexpr int BH  = 36, BW  = 40;  // blurred: (r,c) -> abs (Y0-2+r, X0-2+c)
constexpr int MH  = 34, MW  = 36;  // gradmag: (r,c) -> abs (Y0-1+r, X0-1+c)

__global__ __launch_bounds__(256, 6)
void canny_fused(const float* __restrict__ img,
                 const float* __restrict__ gauss,
                 float* __restrict__ out) {
  __shared__ float s_hb[HBH * HBW];  // per-channel horizontal blur (transient)
  __shared__ float s_bl[BH * BW];    // per-channel blurred (transient)
  __shared__ float s_bs[BH * BW];    // sum over channels of blurred
  __shared__ float s_mg[MH * MW];    // grad_mag summed over channels

  const int tid = threadIdx.x;
  const int X0 = blockIdx.x * TW;
  const int Y0 = blockIdx.y * TH;

  const float g0 = gauss[0], g1 = gauss[1], g2 = gauss[2],
              g3 = gauss[3], g4 = gauss[4];

  for (int ch = 0; ch < 3; ++ch) {
    const float* im = img + (size_t)ch * ((size_t)IMG_H * IMG_W);

    // ---- Stage A: horizontal gaussian, 4 cols per task (40 rows x 10 groups).
    // hblur col c <-> img col X0-2+c; group needs img cols X0-4+c0 .. X0+3+c0.
    for (int j = tid; j < HBH * 10; j += 256) {
      int r = j / 10, g = j - r * 10;
      int c0 = g * 4;
      int gy = Y0 - 4 + r;
      float4 o;
      if ((unsigned)gy < IMG_H) {
        int cb = X0 - 4 + c0;
        const float* row = im + (size_t)gy * IMG_W;
        float a0, a1, a2, a3, a4, a5, a6, a7;
        if (cb >= 0 && cb + 7 < IMG_W) {
          float4 va = *(const float4*)(row + cb);
          float4 vb = *(const float4*)(row + cb + 4);
          a0 = va.x; a1 = va.y; a2 = va.z; a3 = va.w;
          a4 = vb.x; a5 = vb.y; a6 = vb.z; a7 = vb.w;
        } else {
          float t[8];
#pragma unroll
          for (int u = 0; u < 8; ++u) {
            int x = cb + u;
            t[u] = ((unsigned)x < IMG_W) ? row[x] : 0.f;
          }
          a0 = t[0]; a1 = t[1]; a2 = t[2]; a3 = t[3];
          a4 = t[4]; a5 = t[5]; a6 = t[6]; a7 = t[7];
        }
        o.x = g0 * a0 + g1 * a1 + g2 * a2 + g3 * a3 + g4 * a4;
        o.y = g0 * a1 + g1 * a2 + g2 * a3 + g3 * a4 + g4 * a5;
        o.z = g0 * a2 + g1 * a3 + g2 * a4 + g3 * a5 + g4 * a6;
        o.w = g0 * a3 + g1 * a4 + g2 * a5 + g3 * a6 + g4 * a7;
      } else {
        o = make_float4(0.f, 0.f, 0.f, 0.f);
      }
      *(float4*)&s_hb[r * HBW + c0] = o;
    }
    __syncthreads();

    // ---- Stage B: vertical gaussian (36 rows x 10 groups). Force exact 0
    // outside the image (the Sobel conv zero-pads *blurred*).
    for (int j = tid; j < BH * 10; j += 256) {
      int r = j / 10, g = j - r * 10;
      int c0 = g * 4;
      float4 a0 = *(const float4*)&s_hb[(r    ) * HBW + c0];
      float4 a1 = *(const float4*)&s_hb[(r + 1) * HBW + c0];
      float4 a2 = *(const float4*)&s_hb[(r + 2) * HBW + c0];
      float4 a3 = *(const float4*)&s_hb[(r + 3) * HBW + c0];
      float4 a4 = *(const float4*)&s_hb[(r + 4) * HBW + c0];
      float4 v;
      v.x = g0 * a0.x + g1 * a1.x + g2 * a2.x + g3 * a3.x + g4 * a4.x;
      v.y = g0 * a0.y + g1 * a1.y + g2 * a2.y + g3 * a3.y + g4 * a4.y;
      v.z = g0 * a0.z + g1 * a1.z + g2 * a2.z + g3 * a3.z + g4 * a4.z;
      v.w = g0 * a0.w + g1 * a1.w + g2 * a2.w + g3 * a3.w + g4 * a4.w;
      int gy = Y0 - 2 + r;
      bool rok = (unsigned)gy < IMG_H;
      int gx0 = X0 - 2 + c0;
      v.x = (rok && (unsigned)(gx0    ) < IMG_W) ? v.x : 0.f;
      v.y = (rok && (unsigned)(gx0 + 1) < IMG_W) ? v.y : 0.f;
      v.z = (rok && (unsigned)(gx0 + 2) < IMG_W) ? v.z : 0.f;
      v.w = (rok && (unsigned)(gx0 + 3) < IMG_W) ? v.w : 0.f;
      *(float4*)&s_bl[r * BW + c0] = v;
      float4* ps = (float4*)&s_bs[r * BW + c0];
      if (ch == 0) {
        *ps = v;
      } else {
        float4 s = *ps;
        s.x += v.x; s.y += v.y; s.z += v.z; s.w += v.w;
        *ps = s;
      }
    }
    __syncthreads();

    // ---- Stage C: Sobel + magnitude, accumulate (34 rows x 9 groups).
    for (int j = tid; j < MH * 9; j += 256) {
      int r = j / 9, g = j - r * 9;
      int c0 = g * 4;
      float w0[6], w1[6], w2[6];
      {
        float4 p = *(const float4*)&s_bl[(r    ) * BW + c0];
        float2 q = *(const float2*)&s_bl[(r    ) * BW + c0 + 4];
        w0[0]=p.x; w0[1]=p.y; w0[2]=p.z; w0[3]=p.w; w0[4]=q.x; w0[5]=q.y;
      }
      {
        float4 p = *(const float4*)&s_bl[(r + 1) * BW + c0];
        float2 q = *(const float2*)&s_bl[(r + 1) * BW + c0 + 4];
        w1[0]=p.x; w1[1]=p.y; w1[2]=p.z; w1[3]=p.w; w1[4]=q.x; w1[5]=q.y;
      }
      {
        float4 p = *(const float4*)&s_bl[(r + 2) * BW + c0];
        float2 q = *(const float2*)&s_bl[(r + 2) * BW + c0 + 4];
        w2[0]=p.x; w2[1]=p.y; w2[2]=p.z; w2[3]=p.w; w2[4]=q.x; w2[5]=q.y;
      }
      int gy = Y0 - 1 + r;
      bool rok = (unsigned)gy < IMG_H;
      float res[4];
#pragma unroll
      for (int e = 0; e < 4; ++e) {
        float gxv = w0[e] - w0[e + 2] + 2.f * w1[e] - 2.f * w1[e + 2] + w2[e] - w2[e + 2];
        float gyv = w0[e] + 2.f * w0[e + 1] + w0[e + 2] - w2[e] - 2.f * w2[e + 1] - w2[e + 2];
        float m = sqrtf(gxv * gxv + gyv * gyv + 1e-8f);
        int gx = X0 - 1 + c0 + e;
        res[e] = (rok && (unsigned)gx < IMG_W) ? m : 0.f;
      }
      float4* pd = (float4*)&s_mg[r * MW + c0];
      if (ch == 0) {
        *pd = make_float4(res[0], res[1], res[2], res[3]);
      } else {
        float4 s = *pd;
        s.x += res[0]; s.y += res[1]; s.z += res[2]; s.w += res[3];
        *pd = s;
      }
    }
    __syncthreads();
  }

  // ---- Stage D: orientation + NMS + threshold; 4 outputs per thread.
  // dir_w[k] = center - neighbor_k; neighbor LDS offsets dr*MW+dc for
  // k=0..7: 1,37,36,35,-1,-37,-36,-35 (int8-packed). idx_neg = opposite.
  {
    const int ty  = tid >> 3;         // 0..31
    const int tx0 = (tid & 7) << 2;   // 0..28 step 4
    float w0[8], w1[8], w2[8];
#pragma unroll
    for (int rr = 0; rr < 3; ++rr) {
      float* w = (rr == 0) ? w0 : (rr == 1) ? w1 : w2;
      float4 p = *(const float4*)&s_bs[(ty + 1 + rr) * BW + tx0];
      float4 q = *(const float4*)&s_bs[(ty + 1 + rr) * BW + tx0 + 4];
      w[0]=p.x; w[1]=p.y; w[2]=p.z; w[3]=p.w; w[4]=q.x; w[5]=q.y; w[6]=q.z; w[7]=q.w;
    }
    const unsigned long long off_tbl = 0xDDDCDBFF23242501ULL;
    float res[4];
#pragma unroll
    for (int e = 0; e < 4; ++e) {
      int tx = tx0 + e;
      float b00 = w0[e + 1], b01 = w0[e + 2], b02 = w0[e + 3];
      float b10 = w1[e + 1],                  b12 = w1[e + 3];
      float b20 = w2[e + 1], b21 = w2[e + 2], b22 = w2[e + 3];
      float gxs = b00 - b02 + 2.f * b10 - 2.f * b12 + b20 - b22;
      float gys = b00 + 2.f * b01 + b02 - b20 - 2.f * b21 - b22;
      float ori = atan2f(gys, gxs) * 57.295827908797776f + 180.0f;  // 180/3.14159
      int k = (int)rintf(ori / 45.0f);     // round-half-even like jnp.round
      int ip = k & 7;
      int off = (int)(signed char)(off_tbl >> (ip * 8));
      int ctr = (ty + 1) * MW + (tx + 1);
      float mc  = s_mg[ctr];
      float csp = mc - s_mg[ctr + off];
      float csn = mc - s_mg[ctr - off];
      bool is_max = fminf(csp, csn) > 0.0f;
      bool keep = is_max && (mc >= 6.0f) && (mc <= 50.0f);
      res[e] = keep ? 1.0f : 0.0f;
    }
    *(float4*)&out[(size_t)(Y0 + ty) * IMG_W + (X0 + tx0)] =
        make_float4(res[0], res[1], res[2], res[3]);
  }
}

extern "C" void kernel_launch(void* const* d_in, const int* in_sizes, int n_in,
                              void* d_out, int out_size, void* d_ws, size_t ws_size,
                              hipStream_t stream) {
  const float* img   = (const float*)d_in[0];
  const float* gauss = (const float*)d_in[1];
  float* out = (float*)d_out;
  dim3 grid(IMG_W / TW, IMG_H / TH);
  canny_fused<<<grid, 256, 0, stream>>>(img, gauss, out);
}